// Round 1
// baseline (184.927 us; speedup 1.0000x reference)
//
#include <hip/hip_runtime.h>

// ---------------------------------------------------------------------------
// AveragedKeyCircularConvolutionalAttention  (B=2, N=2048, C=768, h=12, d=64)
//
// Math reductions:
//   K_avg[b,h,:]  = x_avg[b,:] @ Wk[h-rows]^T          (K GEMM eliminated)
//   z[b,h,n]      = x[b,n,:] . u[b,h,:],  u = SCALE * K_avg @ Wq[h-rows]
//                                                      (Q GEMM eliminated)
//   attn_n        = softmax(z)/N   (bf16)
//   VT[c, tok]    = (x @ Wv^T)^T   (bf16 MFMA GEMM, transposed output)
//   out_pre[i,dd] = sum_j attn_n[(j-i)%N] * V[j,dd]    (circulant MFMA GEMM)
//   out           = out_pre @ Wp^T + bp                (bf16 MFMA GEMM, f32 out)
// ---------------------------------------------------------------------------

typedef __bf16 bf16x8 __attribute__((ext_vector_type(8)));
typedef float  f32x4  __attribute__((ext_vector_type(4)));

#define AS_GLOBAL(p) ((const __attribute__((address_space(1))) unsigned int*)(p))
#define AS_LDS(p)    ((__attribute__((address_space(3))) unsigned int*)(p))

__device__ __forceinline__ void async16(const void* g, void* l) {
    __builtin_amdgcn_global_load_lds(AS_GLOBAL(g), AS_LDS(l), 16, 0, 0);
}

// ---------------------------------------------------------------------------
// Generic bf16 GEMM:  C[m][n] = sum_k A[m][k] * Bt[n][k]
// BM=BN=128, BK=32, 256 threads (4 waves, 64x64 per wave, 4x4 mfma tiles)
// MODE 0: store bf16      MODE 1: store f32 + bias      MODE 2: z-transposed
// ---------------------------------------------------------------------------
template <int MODE>
__global__ __launch_bounds__(256, 2)
void gemm_bt(const __bf16* __restrict__ A, const __bf16* __restrict__ Bt,
             void* __restrict__ Cout, const float* __restrict__ bias,
             int M, int N, int K, int ldA, int ldBt, int ldC)
{
    __shared__ __attribute__((aligned(16))) __bf16 As[128 * 32];
    __shared__ __attribute__((aligned(16))) __bf16 Bs[128 * 32];

    const int tid = threadIdx.x;
    const int lane = tid & 63, wid = tid >> 6;
    const int lane15 = lane & 15, quad = lane >> 4;
    const int wm = (wid & 1) * 64, wn = (wid >> 1) * 64;
    const int mBase = blockIdx.y * 128, nBase = blockIdx.x * 128;

    f32x4 acc[4][4] = {};

    for (int kb = 0; kb < K; kb += 32) {
        __syncthreads();
        // stage A and B tiles: 512 chunks of 16B each, XOR-swizzled slots
#pragma unroll
        for (int cc = 0; cc < 2; ++cc) {
            int c = tid + cc * 256;              // 0..511
            int row = c >> 2, slot = c & 3;
            int k8 = slot ^ ((row >> 1) & 3);    // swizzle salt
            async16(A  + (size_t)(mBase + row) * ldA  + kb + k8 * 8, &As[c * 8]);
            async16(Bt + (size_t)(nBase + row) * ldBt + kb + k8 * 8, &Bs[c * 8]);
        }
        __syncthreads();

        bf16x8 af[4], bv[4];
#pragma unroll
        for (int mi = 0; mi < 4; ++mi) {
            int row = wm + mi * 16 + lane15;
            af[mi] = *(const bf16x8*)&As[row * 32 + (quad ^ ((row >> 1) & 3)) * 8];
        }
#pragma unroll
        for (int ni = 0; ni < 4; ++ni) {
            int row = wn + ni * 16 + lane15;
            bv[ni] = *(const bf16x8*)&Bs[row * 32 + (quad ^ ((row >> 1) & 3)) * 8];
        }
#pragma unroll
        for (int mi = 0; mi < 4; ++mi)
#pragma unroll
            for (int ni = 0; ni < 4; ++ni)
                acc[mi][ni] = __builtin_amdgcn_mfma_f32_16x16x32_bf16(
                    af[mi], bv[ni], acc[mi][ni], 0, 0, 0);
    }

#pragma unroll
    for (int mi = 0; mi < 4; ++mi)
#pragma unroll
        for (int ni = 0; ni < 4; ++ni)
#pragma unroll
            for (int r = 0; r < 4; ++r) {
                int row = mBase + wm + mi * 16 + quad * 4 + r;
                int col = nBase + wn + ni * 16 + lane15;
                float v = acc[mi][ni][r];
                if (MODE == 0) {
                    ((__bf16*)Cout)[(size_t)row * ldC + col] = (__bf16)v;
                } else if (MODE == 1) {
                    ((float*)Cout)[(size_t)row * ldC + col] = v + bias[col];
                } else { // MODE 2: z_t[o][i], o = b*12+h must match row's b
                    int b = row >> 11;
                    if ((unsigned)(col - b * 12) < 12u)
                        ((float*)Cout)[(size_t)col * 2048 + (row & 2047)] = v;
                }
            }
}

// ---------------------------------------------------------------------------
// Circulant conv:  out_pre[b,i,h,dd] = sum_j attn_n[bh][(j-i)&2047] * V[b,j,h,dd]
// Block: 256 rows(i) x 64 cols(dd) for one (b,h). 4 waves, 64x64 per wave.
// A-frags from 8 shift-replicas of attn in LDS (aligned b128 reads).
// B-frags from V-tile staged via global_load_lds, XOR column swizzle.
// ---------------------------------------------------------------------------
__global__ __launch_bounds__(256, 2)
void conv_k(const __bf16* __restrict__ attn, const __bf16* __restrict__ VT,
            __bf16* __restrict__ outp)
{
    __shared__ __attribute__((aligned(16))) __bf16 rep[8][2056]; // pad: bank salt
    __shared__ __attribute__((aligned(16))) __bf16 vt[64 * 64];

    const int tid = threadIdx.x;
    const int lane = tid & 63, wid = tid >> 6;
    const int lane15 = lane & 15, quad = lane >> 4;
    const int bh = blockIdx.y, b = bh / 12, h = bh % 12;
    const int m0 = blockIdx.x * 256 + wid * 64;

    const __bf16* at = attn + bh * 2048;
    for (int idx = tid; idx < 8 * 2048; idx += 256) {
        int a = idx >> 11, u = idx & 2047;
        rep[a][u] = at[(u + a) & 2047];
    }

    const __bf16* vsrc = VT + (size_t)h * 64 * 4096 + b * 2048;
    f32x4 acc[4][4] = {};

    for (int kb = 0; kb < 32; ++kb) {   // K-step of 64
        __syncthreads();
#pragma unroll
        for (int cc = 0; cc < 2; ++cc) {
            int c = tid + cc * 256;          // 0..511
            int dd = c >> 3, slot = c & 7;
            int k8 = slot ^ (dd & 7);        // swizzle
            async16(vsrc + (size_t)dd * 4096 + kb * 64 + k8 * 8, &vt[c * 8]);
        }
        __syncthreads();

#pragma unroll
        for (int ks = 0; ks < 2; ++ks) {
            int kloc = ks * 32 + quad * 8;
            int kglob = kb * 64 + kloc;
            bf16x8 af[4], bv[4];
#pragma unroll
            for (int mi = 0; mi < 4; ++mi) {
                int m = m0 + mi * 16 + lane15;
                int p = (kglob - m) & 2047;
                int al = p & 7, q = p - al;
                af[mi] = *(const bf16x8*)&rep[al][q];
            }
#pragma unroll
            for (int ni = 0; ni < 4; ++ni) {
                int dd = ni * 16 + lane15;
                int slot = (kloc >> 3) ^ (dd & 7);
                bv[ni] = *(const bf16x8*)&vt[dd * 64 + slot * 8];
            }
#pragma unroll
            for (int mi = 0; mi < 4; ++mi)
#pragma unroll
                for (int ni = 0; ni < 4; ++ni)
                    acc[mi][ni] = __builtin_amdgcn_mfma_f32_16x16x32_bf16(
                        af[mi], bv[ni], acc[mi][ni], 0, 0, 0);
        }
    }

#pragma unroll
    for (int mi = 0; mi < 4; ++mi)
#pragma unroll
        for (int ni = 0; ni < 4; ++ni)
#pragma unroll
            for (int r = 0; r < 4; ++r) {
                int i = m0 + mi * 16 + quad * 4 + r;
                int dd = ni * 16 + lane15;
                outp[(size_t)(b * 2048 + i) * 768 + h * 64 + dd] =
                    (__bf16)acc[mi][ni][r];
            }
}

// ---------------------------------------------------------------------------
// Small kernels
// ---------------------------------------------------------------------------
struct bf4 { __bf16 a, b, c, d; };

__global__ void k_convert(const float4* __restrict__ in, bf4* __restrict__ out, int n4)
{
    int i = blockIdx.x * 256 + threadIdx.x;
    if (i < n4) {
        float4 v = in[i];
        bf4 o{(__bf16)v.x, (__bf16)v.y, (__bf16)v.z, (__bf16)v.w};
        out[i] = o;
    }
}

// x_avg[b][c] += partial sums (x_avg pre-zeroed).  grid (3, 16, 2)
__global__ void k_xavg(const float* __restrict__ x, float* __restrict__ x_avg)
{
    int c = blockIdx.x * 256 + threadIdx.x;   // 0..767
    int b = blockIdx.z;
    int n0 = blockIdx.y * 128;
    const float* p = x + ((size_t)(b * 2048 + n0)) * 768 + c;
    float s = 0.f;
    for (int i = 0; i < 128; ++i) s += p[(size_t)i * 768];
    atomicAdd(&x_avg[b * 768 + c], s);
}

// K_avg[b][o] = (1/2048) * sum_c x_avg[b][c] * Wk[o][c].  384 blocks x 256
__global__ void k_kavg(const float* __restrict__ x_avg, const float* __restrict__ Wk,
                       float* __restrict__ K_avg)
{
    int w = (blockIdx.x * 256 + threadIdx.x) >> 6;  // 0..1535
    int lane = threadIdx.x & 63;
    int b = w / 768, oc = w % 768;
    float s = 0.f;
    for (int c = lane; c < 768; c += 64)
        s += x_avg[b * 768 + c] * Wk[(size_t)oc * 768 + c];
#pragma unroll
    for (int off = 32; off; off >>= 1) s += __shfl_down(s, off);
    if (lane == 0) K_avg[b * 768 + oc] = s * (1.f / 2048.f);
}

// Ub[b*12+h][c] = SCALE * sum_d K_avg[b][h*64+d] * Wq[h*64+d][c].  72 blocks x 256
__global__ void k_u(const float* __restrict__ K_avg, const float* __restrict__ Wq,
                    __bf16* __restrict__ Ub)
{
    int t = blockIdx.x * 256 + threadIdx.x;   // < 18432
    int c = t % 768, bh = t / 768;
    int b = bh / 12, h = bh % 12;
    float s = 0.f;
#pragma unroll 8
    for (int d = 0; d < 64; ++d)
        s += K_avg[b * 768 + h * 64 + d] * Wq[(size_t)(h * 64 + d) * 768 + c];
    Ub[(size_t)bh * 768 + c] = (__bf16)(s * 0.125f);   // SCALE = 64^-0.5
}

// softmax over n per (b,h); writes attn/N as bf16.  24 blocks x 256
__global__ void k_softmax(const float* __restrict__ zt, __bf16* __restrict__ attn)
{
    const int bh = blockIdx.x, tid = threadIdx.x;
    const int lane = tid & 63, wid = tid >> 6;
    __shared__ float red[4];
    const float* z = zt + (size_t)bh * 2048;
    float v[8];
    float m = -1e30f;
#pragma unroll
    for (int j = 0; j < 8; ++j) { v[j] = z[tid + j * 256]; m = fmaxf(m, v[j]); }
#pragma unroll
    for (int off = 32; off; off >>= 1) m = fmaxf(m, __shfl_xor(m, off));
    if (lane == 0) red[wid] = m;
    __syncthreads();
    m = fmaxf(fmaxf(red[0], red[1]), fmaxf(red[2], red[3]));
    __syncthreads();
    float s = 0.f;
#pragma unroll
    for (int j = 0; j < 8; ++j) { v[j] = expf(v[j] - m); s += v[j]; }
#pragma unroll
    for (int off = 32; off; off >>= 1) s += __shfl_xor(s, off);
    if (lane == 0) red[wid] = s;
    __syncthreads();
    s = red[0] + red[1] + red[2] + red[3];
    float inv = 1.f / (s * 2048.f);
#pragma unroll
    for (int j = 0; j < 8; ++j)
        attn[(size_t)bh * 2048 + tid + j * 256] = (__bf16)(v[j] * inv);
}

// ---------------------------------------------------------------------------
extern "C" void kernel_launch(void* const* d_in, const int* in_sizes, int n_in,
                              void* d_out, int out_size, void* d_ws, size_t ws_size,
                              hipStream_t stream)
{
    const float* x  = (const float*)d_in[0];
    const float* Wq = (const float*)d_in[1];
    const float* Wk = (const float*)d_in[2];
    const float* Wv = (const float*)d_in[3];
    const float* Wp = (const float*)d_in[4];
    const float* bp = (const float*)d_in[5];

    char* w = (char*)d_ws;
    auto alloc = [&](size_t bytes) {
        char* p = w; w += (bytes + 255) & ~(size_t)255; return p;
    };
    __bf16* xb     = (__bf16*)alloc((size_t)4096 * 768 * 2);
    __bf16* Wvb    = (__bf16*)alloc((size_t)768 * 768 * 2);
    __bf16* Wpb    = (__bf16*)alloc((size_t)768 * 768 * 2);
    __bf16* Ub     = (__bf16*)alloc((size_t)128 * 768 * 2);
    float*  x_avg  = (float*) alloc((size_t)2 * 768 * 4);
    float*  K_avg  = (float*) alloc((size_t)2 * 768 * 4);
    float*  z_t    = (float*) alloc((size_t)24 * 2048 * 4);
    __bf16* attn_b = (__bf16*)alloc((size_t)24 * 2048 * 2);
    __bf16* VT     = (__bf16*)alloc((size_t)768 * 4096 * 2);
    __bf16* out_pre= (__bf16*)alloc((size_t)4096 * 768 * 2);

    hipMemsetAsync(x_avg, 0, 2 * 768 * sizeof(float), stream);
    hipMemsetAsync(Ub, 0, (size_t)128 * 768 * 2, stream);

    // bf16 conversions
    k_convert<<<3072, 256, 0, stream>>>((const float4*)x,  (bf4*)xb,  786432);
    k_convert<<<576,  256, 0, stream>>>((const float4*)Wv, (bf4*)Wvb, 147456);
    k_convert<<<576,  256, 0, stream>>>((const float4*)Wp, (bf4*)Wpb, 147456);

    // averaged-key path (tiny, fp32)
    k_xavg<<<dim3(3, 16, 2), 256, 0, stream>>>(x, x_avg);
    k_kavg<<<384, 256, 0, stream>>>(x_avg, Wk, K_avg);
    k_u<<<72, 256, 0, stream>>>(K_avg, Wq, Ub);

    // z = xb @ Ub^T  (M=4096, N=128 padded, K=768), stores z_t[o][i]
    gemm_bt<2><<<dim3(1, 32), 256, 0, stream>>>(xb, Ub, z_t, nullptr,
                                                4096, 128, 768, 768, 768, 0);
    k_softmax<<<24, 256, 0, stream>>>(z_t, attn_b);

    // VT = Wv @ x^T  (M=768, N=4096, K=768), bf16 out, ldC=4096
    gemm_bt<0><<<dim3(32, 6), 256, 0, stream>>>(Wvb, xb, VT, nullptr,
                                                768, 4096, 768, 768, 768, 4096);

    // circulant conv -> out_pre[token][c] bf16
    conv_k<<<dim3(8, 24), 256, 0, stream>>>(attn_b, VT, out_pre);

    // out = out_pre @ Wp^T + bp  (f32)
    gemm_bt<1><<<dim3(6, 32), 256, 0, stream>>>(out_pre, Wpb, d_out, bp,
                                                4096, 768, 768, 768, 768, 768);
}